// Round 5
// baseline (271.236 us; speedup 1.0000x reference)
//
#include <hip/hip_runtime.h>
#include <cstdint>
#include <cstddef>

// GCN link prediction: 3x GCNConv(64->64) + ReLU, then 2-layer MLP head.
// N=100k, E=1M, dims 64. Round 14:
//  - agg: 8-lane groups, 32 nodes/block, uint4 (16B/lane) row gathers ->
//    half the gather instructions, 2x rows in flight (R13's srcs prefetch
//    was a no-op => not srcs-latency-bound; betting on gather-issue/MLP).
//  - masked edge slots gather dedicated zero row N (tables now N+1 rows,
//    producer zeroes row N): dup gathers all hit ONE hot line and adds are
//    unconditional (was: random dup row per group + mask fmas).
//  - k_bucket grid 256->1024 (was 1 block/CU, 4 waves/CU latency hiding).
//  - k_zero folded into k_prep (9 -> 7 launches).

#define CDIV(a, b) (((a) + (b) - 1) / (b))

typedef __attribute__((ext_vector_type(8))) short bf16x8;
typedef __attribute__((ext_vector_type(4))) float f32x4;

static constexpr int BKT_SHIFT = 10;            // 1024 nodes per bucket
static constexpr int BKT_NODES = 1 << BKT_SHIFT;
static constexpr int BKT_CAP = 13312;           // mean ~10.2k + ~30 sigma

// Split a into hi (RNE bf16) + lo (truncated bf16 of exact residual).
__device__ __forceinline__ void split_bf(float a, short& hi, short& lo) {
  unsigned u = __float_as_uint(a);
  unsigned r = u + (0x7FFF + ((u >> 16) & 1));  // RNE round to bf16
  hi = (short)(r >> 16);
  float hirec = __uint_as_float(r & 0xFFFF0000u);
  float res = a - hirec;  // exact
  lo = (short)(__float_as_uint(res) >> 16);  // truncate
}

__device__ __forceinline__ unsigned short f2bf_rne(float a) {
  unsigned u = __float_as_uint(a);
  u += 0x7FFF + ((u >> 16) & 1);
  return (unsigned short)(u >> 16);
}

// Pack two float4s (k 0..7 of a row) into hi/lo bf16x8 fragments.
__device__ __forceinline__ void split8(float4 x, float4 y, bf16x8& h, bf16x8& l) {
  float av[8] = {x.x, x.y, x.z, x.w, y.x, y.y, y.z, y.w};
#pragma unroll
  for (int j = 0; j < 8; ++j) {
    short hi, lo;
    split_bf(av[j], hi, lo);
    h[j] = hi;
    l[j] = lo;
  }
}

__device__ __forceinline__ float4 nt_ld4(const float* p) {
  f32x4 v = __builtin_nontemporal_load(reinterpret_cast<const f32x4*>(p));
  float4 r;
  r.x = v[0]; r.y = v[1]; r.z = v[2]; r.w = v[3];
  return r;
}

// Phase 1: partition edges into dst-range buckets (bucket = dst >> 10).
// Per block: LDS histogram of its chunk, one global atomicAdd per non-empty
// bucket to reserve a contiguous run, then write (s,d) pairs into the run.
__global__ __launch_bounds__(256)
void k_bucket(const int* __restrict__ ei, int* __restrict__ bcnt,
              int2* __restrict__ pairs, int E) {
  __shared__ int hist[128], rbase[128], roff[128];
  int t = threadIdx.x;
  int chunk = (E + gridDim.x - 1) / gridDim.x;
  int e0 = blockIdx.x * chunk;
  int e1 = min(e0 + chunk, E);
  if (t < 128) hist[t] = 0;
  __syncthreads();
  for (int e = e0 + t; e < e1; e += 256) {
    int d = __builtin_nontemporal_load(&ei[E + e]);
    atomicAdd(&hist[d >> BKT_SHIFT], 1);
  }
  __syncthreads();
  if (t < 128) {
    roff[t] = 0;
    rbase[t] = hist[t] ? atomicAdd(&bcnt[t], hist[t]) : 0;
  }
  __syncthreads();
  for (int e = e0 + t; e < e1; e += 256) {
    int d = __builtin_nontemporal_load(&ei[E + e]);
    int s = __builtin_nontemporal_load(&ei[e]);
    int b = d >> BKT_SHIFT;
    int r = atomicAdd(&roff[b], 1);
    int idx = rbase[b] + r;
    if (idx < BKT_CAP) pairs[(size_t)b * BKT_CAP + idx] = make_int2(s, d);
  }
}

// Phase 2: one block per bucket. LDS histogram over the bucket's <=1024 dsts,
// Blelloch exclusive scan, emit row_ptr slice + dinv, then scatter srcs via
// LDS cursors. No global atomics.
__global__ __launch_bounds__(1024)
void k_build(const int2* __restrict__ pairs, const int* __restrict__ bcnt,
             int* __restrict__ row_ptr, float* __restrict__ dinv,
             int* __restrict__ srcs, int N, int E, int K) {
  __shared__ int cnt[BKT_NODES];
  __shared__ int deg[BKT_NODES];
  __shared__ int ebase_sh;
  int b = blockIdx.x;
  int t = threadIdx.x;
  int lo = b << BKT_SHIFT;
  int range = min(BKT_NODES, N - lo);
  int sz = min(bcnt[b], BKT_CAP);
  if (t == 0) {
    int s = 0;
    for (int i = 0; i < b; ++i) s += bcnt[i];
    ebase_sh = s;
  }
  cnt[t] = 0;
  __syncthreads();
  int ebase = ebase_sh;
  const int2* pb = pairs + (size_t)b * BKT_CAP;
  for (int i = t; i < sz; i += 1024) {
    atomicAdd(&cnt[pb[i].y - lo], 1);
  }
  __syncthreads();
  deg[t] = cnt[t];
  __syncthreads();
  // Blelloch exclusive scan over cnt[0..1024)
  int offset = 1;
  for (int d2 = BKT_NODES / 2; d2 > 0; d2 >>= 1) {
    if (t < d2) {
      int ai = offset * (2 * t + 1) - 1;
      int bi = offset * (2 * t + 2) - 1;
      cnt[bi] += cnt[ai];
    }
    offset <<= 1;
    __syncthreads();
  }
  if (t == 0) cnt[BKT_NODES - 1] = 0;
  __syncthreads();
  for (int d2 = 1; d2 < BKT_NODES; d2 <<= 1) {
    offset >>= 1;
    if (t < d2) {
      int ai = offset * (2 * t + 1) - 1;
      int bi = offset * (2 * t + 2) - 1;
      int tmp = cnt[ai];
      cnt[ai] = cnt[bi];
      cnt[bi] += tmp;
    }
    __syncthreads();
  }
  // row_ptr + dinv (reads cnt; must complete before fill mutates cnt)
  if (t < range) {
    row_ptr[lo + t] = ebase + cnt[t];
    dinv[lo + t] = rsqrtf((float)deg[t] + 1.0f);
  }
  if (b == K - 1 && t == 0) row_ptr[N] = E;
  __syncthreads();
  // scatter srcs via LDS cursors
  for (int i = t; i < sz; i += 1024) {
    int2 p = pb[i];
    int pos = ebase + atomicAdd(&cnt[p.y - lo], 1);
    srcs[pos] = p.x;
  }
}

// Pre-split 5 weight matrices (64x64, [in,out] row-major) into hi/lo bf16
// fragments, packed: packed[mat*1024 + ((t*2+q)*2+h)*64 + lane].
// Block 5 zeroes bcnt (folded k_zero launch).
__global__ void k_prep(const float* __restrict__ w0, const float* __restrict__ w1,
                       const float* __restrict__ w2, const float* __restrict__ w3,
                       const float* __restrict__ w4, bf16x8* __restrict__ packed,
                       int* __restrict__ bcnt) {
  if (blockIdx.x == 5) {
    if (threadIdx.x < 128) bcnt[threadIdx.x] = 0;
    return;
  }
  const float* W;
  switch (blockIdx.x) {
    case 0: W = w0; break;
    case 1: W = w1; break;
    case 2: W = w2; break;
    case 3: W = w3; break;
    default: W = w4; break;
  }
  int tid = threadIdx.x;  // 0..511
  int lane = tid & 63;
  int q = (tid >> 6) & 1;
  int t = tid >> 7;
  int col = lane & 15, quad = lane >> 4;
  bf16x8 hi8, lo8;
#pragma unroll
  for (int j = 0; j < 8; ++j) {
    int k = q * 32 + quad * 8 + j;
    short hi, lo;
    split_bf(W[k * 64 + t * 16 + col], hi, lo);
    hi8[j] = hi;
    lo8[j] = lo;
  }
  size_t base = (size_t)blockIdx.x * 1024 + ((t * 2 + q) * 2) * 64 + lane;
  packed[base] = hi8;
  packed[base + 64] = lo8;
}

// C[n x 64] = A @ W (*dinv[row]), bf16 out (gather-table producer; row n of
// out zeroed by block 0 -- the shared "masked gather" target). One 16-row
// tile per wave. A input is read-once -> non-temporal loads.
// Verified layouts: A[m=lane&15][k=quad*8+j]; B[k][n=lane&15];
// C col=lane&15, row=quad*4+reg.
__global__ __launch_bounds__(256, 4)
void k_mm(const float* __restrict__ in, const bf16x8* __restrict__ Wp,
          const float* __restrict__ dinv, unsigned short* __restrict__ out, int n) {
  if (blockIdx.x == 0 && threadIdx.x < 32) {
    ((unsigned int*)out)[(size_t)n * 32 + threadIdx.x] = 0u;  // zero row n
  }
  int lane = threadIdx.x & 63;
  int col = lane & 15, quad = lane >> 4;
  int tile = (blockIdx.x * blockDim.x + threadIdx.x) >> 6;
  int ntiles = (n + 15) >> 4;
  if (tile >= ntiles) return;

  bf16x8 wh[4][2], wl[4][2];
#pragma unroll
  for (int t = 0; t < 4; ++t)
#pragma unroll
    for (int q = 0; q < 2; ++q) {
      wh[t][q] = Wp[((t * 2 + q) * 2) * 64 + lane];
      wl[t][q] = Wp[((t * 2 + q) * 2 + 1) * 64 + lane];
    }

  int row0 = tile << 4;
  int ar = row0 + col;
  if (ar > n - 1) ar = n - 1;  // clamp; stores guarded
  const float* arow = in + (size_t)ar * 64 + quad * 8;
  float4 a0 = nt_ld4(arow), a1 = nt_ld4(arow + 4);
  float4 a2 = nt_ld4(arow + 32), a3 = nt_ld4(arow + 36);

  bf16x8 ah[2], al[2];
  split8(a0, a1, ah[0], al[0]);
  split8(a2, a3, ah[1], al[1]);

  f32x4 acc[4];
#pragma unroll
  for (int t = 0; t < 4; ++t) acc[t] = (f32x4){0.f, 0.f, 0.f, 0.f};
#pragma unroll
  for (int t = 0; t < 4; ++t)
#pragma unroll
    for (int q = 0; q < 2; ++q) {
      acc[t] = __builtin_amdgcn_mfma_f32_16x16x32_bf16(ah[q], wh[t][q], acc[t], 0, 0, 0);
      acc[t] = __builtin_amdgcn_mfma_f32_16x16x32_bf16(ah[q], wl[t][q], acc[t], 0, 0, 0);
      acc[t] = __builtin_amdgcn_mfma_f32_16x16x32_bf16(al[q], wh[t][q], acc[t], 0, 0, 0);
    }
  float dv[4];
#pragma unroll
  for (int r = 0; r < 4; ++r) {
    int row = row0 + quad * 4 + r;
    dv[r] = (row < n) ? dinv[row] : 0.0f;
  }
#pragma unroll
  for (int t = 0; t < 4; ++t)
#pragma unroll
    for (int r = 0; r < 4; ++r) {
      int row = row0 + quad * 4 + r;
      if (row < n) out[(size_t)row * 64 + t * 16 + col] = f2bf_rne(acc[t][r] * dv[r]);
    }
}

// Fused aggregate + mm. Block = 256 threads = 32 nodes (two mm row-tiles).
// Agg: lane-group g (8 lanes) owns node row0+g; lane fg owns 16B (8 bf16) of
// the 128B row -> uint4 gathers, 8-deep software-pipelined edge walk (srcs
// indices for iter k+1 prefetched under iter k's row gathers). Masked slots
// gather the all-zero row n (one shared hot line) and adds are unconditional.
// MM: each wave computes one 16-col stripe for BOTH 16-row tiles.
//   HEAD=false: out = bf16((a@Wp1)*dinv[row]) (next hws table; zeroes row n)
//   HEAD=true:  h4 = relu(a@Wp1+b1p) -> LDS; out = fp32(h4@Wp2+b2p)
template <bool HEAD>
__global__ __launch_bounds__(256, 4)
void k_agg_mm(const unsigned short* __restrict__ hws, const float* __restrict__ dinv,
              const int* __restrict__ row_ptr, const int* __restrict__ srcs,
              const float* __restrict__ bagg,
              const bf16x8* __restrict__ Wp1, const float* __restrict__ b1p,
              const bf16x8* __restrict__ Wp2, const float* __restrict__ b2p,
              void* __restrict__ out, int n) {
  constexpr int LDP = 68;  // fp32 row pad
  __shared__ float a_sh[32 * LDP];
  int tid = threadIdx.x;
  int g = tid >> 3;   // node group 0..31
  int fg = tid & 7;   // 8-bf16 (16B) feature group
  int row0 = blockIdx.x << 5;
  const uint4* hw4 = (const uint4*)hws;  // row = 8 x uint4

  if (!HEAD && blockIdx.x == 0 && tid < 32) {
    ((unsigned int*)out)[(size_t)n * 32 + tid] = 0u;  // zero row n of next table
  }

  int node = row0 + g;
  bool valid = node < n;
  int nd = valid ? node : n;             // invalid -> zero row
  uint4 su = hw4[(size_t)nd * 8 + fg];   // self row, issued early
  float di = valid ? dinv[node] : 0.f;
  int p0 = 0, p1 = 0;
  if (valid) {
    p0 = row_ptr[node];
    p1 = row_ptr[node + 1];
  }
  float acc[8] = {0.f, 0.f, 0.f, 0.f, 0.f, 0.f, 0.f, 0.f};
  if (p0 < p1) {
    int s[8];
#pragma unroll
    for (int j = 0; j < 8; ++j) {
      int ij = p0 + j;
      bool ok = ij < p1;
      int sv = __builtin_nontemporal_load(&srcs[ok ? ij : p1 - 1]);
      s[j] = ok ? sv : n;  // masked -> zero row
    }
    for (int p = p0; p < p1; p += 8) {
      uint4 u[8];
#pragma unroll
      for (int j = 0; j < 8; ++j) u[j] = hw4[(size_t)s[j] * 8 + fg];
      int pn = p + 8;
      if (pn < p1) {
#pragma unroll
        for (int j = 0; j < 8; ++j) {
          int ij = pn + j;
          bool ok = ij < p1;
          int sv = __builtin_nontemporal_load(&srcs[ok ? ij : p1 - 1]);
          s[j] = ok ? sv : n;
        }
      }
#pragma unroll
      for (int j = 0; j < 8; ++j) {
        acc[0] += __uint_as_float(u[j].x << 16);
        acc[1] += __uint_as_float(u[j].x & 0xFFFF0000u);
        acc[2] += __uint_as_float(u[j].y << 16);
        acc[3] += __uint_as_float(u[j].y & 0xFFFF0000u);
        acc[4] += __uint_as_float(u[j].z << 16);
        acc[5] += __uint_as_float(u[j].z & 0xFFFF0000u);
        acc[6] += __uint_as_float(u[j].w << 16);
        acc[7] += __uint_as_float(u[j].w & 0xFFFF0000u);
      }
    }
  }
  {
    float sf[8];
    sf[0] = __uint_as_float(su.x << 16);
    sf[1] = __uint_as_float(su.x & 0xFFFF0000u);
    sf[2] = __uint_as_float(su.y << 16);
    sf[3] = __uint_as_float(su.y & 0xFFFF0000u);
    sf[4] = __uint_as_float(su.z << 16);
    sf[5] = __uint_as_float(su.z & 0xFFFF0000u);
    sf[6] = __uint_as_float(su.w << 16);
    sf[7] = __uint_as_float(su.w & 0xFFFF0000u);
    float r[8];
#pragma unroll
    for (int k = 0; k < 8; ++k) {
      float bk = bagg[fg * 8 + k];
      r[k] = valid ? fmaxf(fmaf(di, acc[k] + sf[k], bk), 0.f) : 0.f;
    }
    float* dst = &a_sh[g * LDP + (fg << 3)];
    *(float4*)(dst) = make_float4(r[0], r[1], r[2], r[3]);
    *(float4*)(dst + 4) = make_float4(r[4], r[5], r[6], r[7]);
  }
  __syncthreads();

  // ---- mm phase: wave covers cols wave*16..+15 for both 16-row tiles ----
  int lane = tid & 63;
  int wave = tid >> 6;
  int col = lane & 15, quad = lane >> 4;

  bf16x8 wh[2], wl[2];
#pragma unroll
  for (int q = 0; q < 2; ++q) {
    wh[q] = Wp1[((wave * 2 + q) * 2) * 64 + lane];
    wl[q] = Wp1[((wave * 2 + q) * 2 + 1) * 64 + lane];
  }
  f32x4 acc1[2];
#pragma unroll
  for (int rt = 0; rt < 2; ++rt) {
    const float* arow = &a_sh[(rt * 16 + col) * LDP + (quad << 3)];
    float4 a0 = *(const float4*)(arow);
    float4 a1 = *(const float4*)(arow + 4);
    float4 a2 = *(const float4*)(arow + 32);
    float4 a3 = *(const float4*)(arow + 36);
    bf16x8 ah[2], al[2];
    split8(a0, a1, ah[0], al[0]);
    split8(a2, a3, ah[1], al[1]);
    acc1[rt] = (f32x4){0.f, 0.f, 0.f, 0.f};
#pragma unroll
    for (int q = 0; q < 2; ++q) {
      acc1[rt] = __builtin_amdgcn_mfma_f32_16x16x32_bf16(ah[q], wh[q], acc1[rt], 0, 0, 0);
      acc1[rt] = __builtin_amdgcn_mfma_f32_16x16x32_bf16(ah[q], wl[q], acc1[rt], 0, 0, 0);
      acc1[rt] = __builtin_amdgcn_mfma_f32_16x16x32_bf16(al[q], wh[q], acc1[rt], 0, 0, 0);
    }
  }

  if constexpr (!HEAD) {
#pragma unroll
    for (int rt = 0; rt < 2; ++rt)
#pragma unroll
      for (int r = 0; r < 4; ++r) {
        int row = row0 + rt * 16 + (quad << 2) + r;
        if (row < n) {
          ((unsigned short*)out)[(size_t)row * 64 + wave * 16 + col] =
              f2bf_rne(acc1[rt][r] * dinv[row]);
        }
      }
  } else {
    __shared__ float h_sh[32 * LDP];
    float bv1 = b1p[wave * 16 + col];
#pragma unroll
    for (int rt = 0; rt < 2; ++rt)
#pragma unroll
      for (int r = 0; r < 4; ++r) {
        h_sh[(rt * 16 + (quad << 2) + r) * LDP + wave * 16 + col] =
            fmaxf(acc1[rt][r] + bv1, 0.f);
      }
    __syncthreads();
    bf16x8 wh2[2], wl2[2];
#pragma unroll
    for (int q = 0; q < 2; ++q) {
      wh2[q] = Wp2[((wave * 2 + q) * 2) * 64 + lane];
      wl2[q] = Wp2[((wave * 2 + q) * 2 + 1) * 64 + lane];
    }
    float bv2 = b2p[wave * 16 + col];
#pragma unroll
    for (int rt = 0; rt < 2; ++rt) {
      const float* hrow = &h_sh[(rt * 16 + col) * LDP + (quad << 3)];
      float4 h0 = *(const float4*)(hrow);
      float4 h1 = *(const float4*)(hrow + 4);
      float4 h2 = *(const float4*)(hrow + 32);
      float4 h3 = *(const float4*)(hrow + 36);
      bf16x8 ah2[2], al2[2];
      split8(h0, h1, ah2[0], al2[0]);
      split8(h2, h3, ah2[1], al2[1]);
      f32x4 acc2 = (f32x4){0.f, 0.f, 0.f, 0.f};
#pragma unroll
      for (int q = 0; q < 2; ++q) {
        acc2 = __builtin_amdgcn_mfma_f32_16x16x32_bf16(ah2[q], wh2[q], acc2, 0, 0, 0);
        acc2 = __builtin_amdgcn_mfma_f32_16x16x32_bf16(ah2[q], wl2[q], acc2, 0, 0, 0);
        acc2 = __builtin_amdgcn_mfma_f32_16x16x32_bf16(al2[q], wh2[q], acc2, 0, 0, 0);
      }
#pragma unroll
      for (int r = 0; r < 4; ++r) {
        int row = row0 + rt * 16 + (quad << 2) + r;
        if (row < n) {
          ((float*)out)[(size_t)row * 64 + wave * 16 + col] = acc2[r] + bv2;
        }
      }
    }
  }
}

extern "C" void kernel_launch(void* const* d_in, const int* in_sizes, int n_in,
                              void* d_out, int out_size, void* d_ws, size_t ws_size,
                              hipStream_t stream) {
  const float* x = (const float*)d_in[0];
  const int* ei = (const int*)d_in[1];  // int32 per harness convention
  const float* W1 = (const float*)d_in[2];
  const float* b1 = (const float*)d_in[3];
  const float* W2 = (const float*)d_in[4];
  const float* b2 = (const float*)d_in[5];
  const float* W3 = (const float*)d_in[6];
  const float* b3 = (const float*)d_in[7];
  const float* fw1 = (const float*)d_in[8];
  const float* fb1 = (const float*)d_in[9];
  const float* fw2 = (const float*)d_in[10];
  const float* fb2 = (const float*)d_in[11];
  float* out = (float*)d_out;

  const int N = in_sizes[0] / 64;
  const int E = in_sizes[1] / 2;
  const int K = CDIV(N, BKT_NODES);  // buckets (98 for N=100k)

  // workspace (~31 MB)
  char* w = (char*)d_ws;
  auto take = [&](size_t bytes) -> char* {
    char* p = w;
    w += (bytes + 255) & ~(size_t)255;
    return p;
  };
  float* dinv = (float*)take((size_t)N * 4);
  int* row_ptr = (int*)take((size_t)(N + 1) * 4);
  int* bcnt = (int*)take((size_t)128 * 4);
  int* srcs = (int*)take((size_t)E * 4);
  bf16x8* wpack = (bf16x8*)take((size_t)5 * 1024 * 16);                  // 80 KB
  unsigned short* hwsA = (unsigned short*)take((size_t)(N + 1) * 64 * 2);  // 12.8 MB (+zero row)
  unsigned short* hwsB = (unsigned short*)take((size_t)(N + 1) * 64 * 2);  // 12.8 MB
  int2* pairs = (int2*)hwsA;  // 10.4 MB alias; consumed before k_mm writes hwsA

  const int B = 256;

  // ---- weight prep (+bcnt zero) + CSR build (atomic-free) ----
  k_prep<<<6, 512, 0, stream>>>(W1, W2, W3, fw1, fw2, wpack, bcnt);
  k_bucket<<<1024, B, 0, stream>>>(ei, bcnt, pairs, E);
  k_build<<<K, 1024, 0, stream>>>(pairs, bcnt, row_ptr, dinv, srcs, N, E, K);

  const int ntiles16 = CDIV(N, 16);
  const int MMG = CDIV(ntiles16, 4);   // k_mm: 1 tile/wave, 4 waves/block
  const int ntiles32 = CDIV(N, 32);    // agg_mm: 32 nodes/block

  // hws1 = bf16((x@W1)*dinv)
  k_mm<<<MMG, B, 0, stream>>>(x, wpack + 0 * 1024, dinv, hwsA, N);
  // h1 = relu(dinv*(agg+self)+b1); hws2 = bf16((h1@W2)*dinv)
  k_agg_mm<false><<<ntiles32, B, 0, stream>>>(hwsA, dinv, row_ptr, srcs, b1,
                                              wpack + 1 * 1024, nullptr, nullptr, nullptr,
                                              hwsB, N);
  // h2; hws3 = bf16((h2@W3)*dinv)
  k_agg_mm<false><<<ntiles32, B, 0, stream>>>(hwsB, dinv, row_ptr, srcs, b2,
                                              wpack + 2 * 1024, nullptr, nullptr, nullptr,
                                              hwsA, N);
  // h3; h4 = relu(h3@fw1+fb1); out = h4@fw2+fb2 (fp32)
  k_agg_mm<true><<<ntiles32, B, 0, stream>>>(hwsA, dinv, row_ptr, srcs, b3,
                                             wpack + 3 * 1024, fb1, wpack + 4 * 1024, fb2,
                                             out, N);
}

// Round 6
// 260.043 us; speedup vs baseline: 1.0430x; 1.0430x over previous
//
#include <hip/hip_runtime.h>
#include <cstdint>
#include <cstddef>

// GCN link prediction: 3x GCNConv(64->64) + ReLU, then 2-layer MLP head.
// N=100k, E=1M, dims 64. Round 15:
//  - agg reverted to r13 shape (16-lane groups, 16 nodes/block, uint2 8B
//    gathers, 8-deep pipelined srcs prefetch) -- r14's 8-lane/32-node variant
//    dropped occupancy 67->36% (LDS doubled via h_sh materializing in BOTH
//    template instantiations + VGPR 52) and regressed 40->50us.
//  - kept from r14: masked slots gather dedicated zero row n (one L1-hot
//    line, unconditional adds), k_bucket<<<1024>>>, k_zero folded into
//    k_prep.
//  - HEAD variant now REUSES a_sh for h (2 extra barriers) -> LDS 4352B in
//    all variants (was 17408), restoring occupancy.

#define CDIV(a, b) (((a) + (b) - 1) / (b))

typedef __attribute__((ext_vector_type(8))) short bf16x8;
typedef __attribute__((ext_vector_type(4))) float f32x4;

static constexpr int BKT_SHIFT = 10;            // 1024 nodes per bucket
static constexpr int BKT_NODES = 1 << BKT_SHIFT;
static constexpr int BKT_CAP = 13312;           // mean ~10.2k + ~30 sigma

// Split a into hi (RNE bf16) + lo (truncated bf16 of exact residual).
__device__ __forceinline__ void split_bf(float a, short& hi, short& lo) {
  unsigned u = __float_as_uint(a);
  unsigned r = u + (0x7FFF + ((u >> 16) & 1));  // RNE round to bf16
  hi = (short)(r >> 16);
  float hirec = __uint_as_float(r & 0xFFFF0000u);
  float res = a - hirec;  // exact
  lo = (short)(__float_as_uint(res) >> 16);  // truncate
}

__device__ __forceinline__ unsigned short f2bf_rne(float a) {
  unsigned u = __float_as_uint(a);
  u += 0x7FFF + ((u >> 16) & 1);
  return (unsigned short)(u >> 16);
}

__device__ __forceinline__ float4 bf4_to_f4(uint2 u) {
  float4 v;
  v.x = __uint_as_float(u.x << 16);
  v.y = __uint_as_float(u.x & 0xFFFF0000u);
  v.z = __uint_as_float(u.y << 16);
  v.w = __uint_as_float(u.y & 0xFFFF0000u);
  return v;
}

// Pack two float4s (k 0..7 of a row) into hi/lo bf16x8 fragments.
__device__ __forceinline__ void split8(float4 x, float4 y, bf16x8& h, bf16x8& l) {
  float av[8] = {x.x, x.y, x.z, x.w, y.x, y.y, y.z, y.w};
#pragma unroll
  for (int j = 0; j < 8; ++j) {
    short hi, lo;
    split_bf(av[j], hi, lo);
    h[j] = hi;
    l[j] = lo;
  }
}

__device__ __forceinline__ float4 nt_ld4(const float* p) {
  f32x4 v = __builtin_nontemporal_load(reinterpret_cast<const f32x4*>(p));
  float4 r;
  r.x = v[0]; r.y = v[1]; r.z = v[2]; r.w = v[3];
  return r;
}

// Phase 1: partition edges into dst-range buckets (bucket = dst >> 10).
// Per block: LDS histogram of its chunk, one global atomicAdd per non-empty
// bucket to reserve a contiguous run, then write (s,d) pairs into the run.
__global__ __launch_bounds__(256)
void k_bucket(const int* __restrict__ ei, int* __restrict__ bcnt,
              int2* __restrict__ pairs, int E) {
  __shared__ int hist[128], rbase[128], roff[128];
  int t = threadIdx.x;
  int chunk = (E + gridDim.x - 1) / gridDim.x;
  int e0 = blockIdx.x * chunk;
  int e1 = min(e0 + chunk, E);
  if (t < 128) hist[t] = 0;
  __syncthreads();
  for (int e = e0 + t; e < e1; e += 256) {
    int d = __builtin_nontemporal_load(&ei[E + e]);
    atomicAdd(&hist[d >> BKT_SHIFT], 1);
  }
  __syncthreads();
  if (t < 128) {
    roff[t] = 0;
    rbase[t] = hist[t] ? atomicAdd(&bcnt[t], hist[t]) : 0;
  }
  __syncthreads();
  for (int e = e0 + t; e < e1; e += 256) {
    int d = __builtin_nontemporal_load(&ei[E + e]);
    int s = __builtin_nontemporal_load(&ei[e]);
    int b = d >> BKT_SHIFT;
    int r = atomicAdd(&roff[b], 1);
    int idx = rbase[b] + r;
    if (idx < BKT_CAP) pairs[(size_t)b * BKT_CAP + idx] = make_int2(s, d);
  }
}

// Phase 2: one block per bucket. LDS histogram over the bucket's <=1024 dsts,
// Blelloch exclusive scan, emit row_ptr slice + dinv, then scatter srcs via
// LDS cursors. No global atomics.
__global__ __launch_bounds__(1024)
void k_build(const int2* __restrict__ pairs, const int* __restrict__ bcnt,
             int* __restrict__ row_ptr, float* __restrict__ dinv,
             int* __restrict__ srcs, int N, int E, int K) {
  __shared__ int cnt[BKT_NODES];
  __shared__ int deg[BKT_NODES];
  __shared__ int ebase_sh;
  int b = blockIdx.x;
  int t = threadIdx.x;
  int lo = b << BKT_SHIFT;
  int range = min(BKT_NODES, N - lo);
  int sz = min(bcnt[b], BKT_CAP);
  if (t == 0) {
    int s = 0;
    for (int i = 0; i < b; ++i) s += bcnt[i];
    ebase_sh = s;
  }
  cnt[t] = 0;
  __syncthreads();
  int ebase = ebase_sh;
  const int2* pb = pairs + (size_t)b * BKT_CAP;
  for (int i = t; i < sz; i += 1024) {
    atomicAdd(&cnt[pb[i].y - lo], 1);
  }
  __syncthreads();
  deg[t] = cnt[t];
  __syncthreads();
  // Blelloch exclusive scan over cnt[0..1024)
  int offset = 1;
  for (int d2 = BKT_NODES / 2; d2 > 0; d2 >>= 1) {
    if (t < d2) {
      int ai = offset * (2 * t + 1) - 1;
      int bi = offset * (2 * t + 2) - 1;
      cnt[bi] += cnt[ai];
    }
    offset <<= 1;
    __syncthreads();
  }
  if (t == 0) cnt[BKT_NODES - 1] = 0;
  __syncthreads();
  for (int d2 = 1; d2 < BKT_NODES; d2 <<= 1) {
    offset >>= 1;
    if (t < d2) {
      int ai = offset * (2 * t + 1) - 1;
      int bi = offset * (2 * t + 2) - 1;
      int tmp = cnt[ai];
      cnt[ai] = cnt[bi];
      cnt[bi] += tmp;
    }
    __syncthreads();
  }
  // row_ptr + dinv (reads cnt; must complete before fill mutates cnt)
  if (t < range) {
    row_ptr[lo + t] = ebase + cnt[t];
    dinv[lo + t] = rsqrtf((float)deg[t] + 1.0f);
  }
  if (b == K - 1 && t == 0) row_ptr[N] = E;
  __syncthreads();
  // scatter srcs via LDS cursors
  for (int i = t; i < sz; i += 1024) {
    int2 p = pb[i];
    int pos = ebase + atomicAdd(&cnt[p.y - lo], 1);
    srcs[pos] = p.x;
  }
}

// Pre-split 5 weight matrices (64x64, [in,out] row-major) into hi/lo bf16
// fragments, packed: packed[mat*1024 + ((t*2+q)*2+h)*64 + lane].
// Block 5 zeroes bcnt (folded k_zero launch).
__global__ void k_prep(const float* __restrict__ w0, const float* __restrict__ w1,
                       const float* __restrict__ w2, const float* __restrict__ w3,
                       const float* __restrict__ w4, bf16x8* __restrict__ packed,
                       int* __restrict__ bcnt) {
  if (blockIdx.x == 5) {
    if (threadIdx.x < 128) bcnt[threadIdx.x] = 0;
    return;
  }
  const float* W;
  switch (blockIdx.x) {
    case 0: W = w0; break;
    case 1: W = w1; break;
    case 2: W = w2; break;
    case 3: W = w3; break;
    default: W = w4; break;
  }
  int tid = threadIdx.x;  // 0..511
  int lane = tid & 63;
  int q = (tid >> 6) & 1;
  int t = tid >> 7;
  int col = lane & 15, quad = lane >> 4;
  bf16x8 hi8, lo8;
#pragma unroll
  for (int j = 0; j < 8; ++j) {
    int k = q * 32 + quad * 8 + j;
    short hi, lo;
    split_bf(W[k * 64 + t * 16 + col], hi, lo);
    hi8[j] = hi;
    lo8[j] = lo;
  }
  size_t base = (size_t)blockIdx.x * 1024 + ((t * 2 + q) * 2) * 64 + lane;
  packed[base] = hi8;
  packed[base + 64] = lo8;
}

// C[n x 64] = A @ W (*dinv[row]), bf16 out (gather-table producer; row n of
// out zeroed by block 0 -- the shared "masked gather" target). One 16-row
// tile per wave. A input is read-once -> non-temporal loads.
// Verified layouts: A[m=lane&15][k=quad*8+j]; B[k][n=lane&15];
// C col=lane&15, row=quad*4+reg.
__global__ __launch_bounds__(256, 4)
void k_mm(const float* __restrict__ in, const bf16x8* __restrict__ Wp,
          const float* __restrict__ dinv, unsigned short* __restrict__ out, int n) {
  if (blockIdx.x == 0 && threadIdx.x < 32) {
    ((unsigned int*)out)[(size_t)n * 32 + threadIdx.x] = 0u;  // zero row n
  }
  int lane = threadIdx.x & 63;
  int col = lane & 15, quad = lane >> 4;
  int tile = (blockIdx.x * blockDim.x + threadIdx.x) >> 6;
  int ntiles = (n + 15) >> 4;
  if (tile >= ntiles) return;

  bf16x8 wh[4][2], wl[4][2];
#pragma unroll
  for (int t = 0; t < 4; ++t)
#pragma unroll
    for (int q = 0; q < 2; ++q) {
      wh[t][q] = Wp[((t * 2 + q) * 2) * 64 + lane];
      wl[t][q] = Wp[((t * 2 + q) * 2 + 1) * 64 + lane];
    }

  int row0 = tile << 4;
  int ar = row0 + col;
  if (ar > n - 1) ar = n - 1;  // clamp; stores guarded
  const float* arow = in + (size_t)ar * 64 + quad * 8;
  float4 a0 = nt_ld4(arow), a1 = nt_ld4(arow + 4);
  float4 a2 = nt_ld4(arow + 32), a3 = nt_ld4(arow + 36);

  bf16x8 ah[2], al[2];
  split8(a0, a1, ah[0], al[0]);
  split8(a2, a3, ah[1], al[1]);

  f32x4 acc[4];
#pragma unroll
  for (int t = 0; t < 4; ++t) acc[t] = (f32x4){0.f, 0.f, 0.f, 0.f};
#pragma unroll
  for (int t = 0; t < 4; ++t)
#pragma unroll
    for (int q = 0; q < 2; ++q) {
      acc[t] = __builtin_amdgcn_mfma_f32_16x16x32_bf16(ah[q], wh[t][q], acc[t], 0, 0, 0);
      acc[t] = __builtin_amdgcn_mfma_f32_16x16x32_bf16(ah[q], wl[t][q], acc[t], 0, 0, 0);
      acc[t] = __builtin_amdgcn_mfma_f32_16x16x32_bf16(al[q], wh[t][q], acc[t], 0, 0, 0);
    }
  float dv[4];
#pragma unroll
  for (int r = 0; r < 4; ++r) {
    int row = row0 + quad * 4 + r;
    dv[r] = (row < n) ? dinv[row] : 0.0f;
  }
#pragma unroll
  for (int t = 0; t < 4; ++t)
#pragma unroll
    for (int r = 0; r < 4; ++r) {
      int row = row0 + quad * 4 + r;
      if (row < n) out[(size_t)row * 64 + t * 16 + col] = f2bf_rne(acc[t][r] * dv[r]);
    }
}

// Fused aggregate + mm. Block = 256 threads = 16 nodes (one mm tile).
// Agg: lane-group g (16 lanes) owns node row0+g; lane fg owns 8B (4 bf16) of
// the 128B row. 8-deep software-pipelined edge walk (next 8 srcs prefetched
// under current 8 row gathers); masked slots gather the all-zero row n (one
// shared L1-hot line) so adds are unconditional. 32 row-gathers in flight
// per wave, no cross-lane reduction.
// MM: each wave computes one 16-col stripe of the 16x64 split-bf16 mm.
//   HEAD=false: out = bf16((a@Wp1)*dinv[row]) (next hws table; zeroes row n)
//   HEAD=true:  h4 = relu(a@Wp1+b1p) -> a_sh (reused); out = fp32(h4@Wp2+b2p)
template <bool HEAD>
__global__ __launch_bounds__(256, 4)
void k_agg_mm(const unsigned short* __restrict__ hws, const float* __restrict__ dinv,
              const int* __restrict__ row_ptr, const int* __restrict__ srcs,
              const float* __restrict__ bagg,
              const bf16x8* __restrict__ Wp1, const float* __restrict__ b1p,
              const bf16x8* __restrict__ Wp2, const float* __restrict__ b2p,
              void* __restrict__ out, int n) {
  constexpr int LDP = 68;  // fp32 row pad: 16B-aligned float4s, ~2-way banks
  __shared__ float a_sh[16 * LDP];
  int tid = threadIdx.x;
  int g = tid >> 4;    // node group 0..15
  int fg = tid & 15;   // 4-bf16 feature group
  int row0 = blockIdx.x << 4;
  const uint2* hw2 = (const uint2*)hws;  // row = 16 x uint2

  if (!HEAD && blockIdx.x == 0 && tid < 32) {
    ((unsigned int*)out)[(size_t)n * 32 + tid] = 0u;  // zero row n of next table
  }

  int node = row0 + g;
  bool valid = node < n;
  int nd = valid ? node : n;             // invalid -> zero row
  uint2 su = hw2[(size_t)nd * 16 + fg];  // self row gather, issued early
  float di = valid ? dinv[node] : 0.f;
  int p0 = 0, p1 = 0;
  if (valid) {
    p0 = row_ptr[node];
    p1 = row_ptr[node + 1];
  }
  float4 acc = make_float4(0.f, 0.f, 0.f, 0.f);
  if (p0 < p1) {
    int s[8];
#pragma unroll
    for (int j = 0; j < 8; ++j) {
      int ij = p0 + j;
      bool ok = ij < p1;
      int sv = __builtin_nontemporal_load(&srcs[ok ? ij : p1 - 1]);
      s[j] = ok ? sv : n;  // masked -> zero row
    }
    for (int p = p0; p < p1; p += 8) {
      // issue current 8 row gathers
      uint2 u[8];
#pragma unroll
      for (int j = 0; j < 8; ++j) u[j] = hw2[(size_t)s[j] * 16 + fg];
      // prefetch next 8 srcs indices (overlaps with row gathers)
      int pn = p + 8;
      if (pn < p1) {
#pragma unroll
        for (int j = 0; j < 8; ++j) {
          int ij = pn + j;
          bool ok = ij < p1;
          int sv = __builtin_nontemporal_load(&srcs[ok ? ij : p1 - 1]);
          s[j] = ok ? sv : n;
        }
      }
      // accumulate, unconditional (masked slots hit the zero row)
#pragma unroll
      for (int j = 0; j < 8; ++j) {
        float4 v = bf4_to_f4(u[j]);
        acc.x += v.x;
        acc.y += v.y;
        acc.z += v.z;
        acc.w += v.w;
      }
    }
  }
  {
    float4 selfv = bf4_to_f4(su);
    float4 b4 = ((const float4*)bagg)[fg];
    float4 r = make_float4(0.f, 0.f, 0.f, 0.f);
    if (valid) {
      r.x = fmaxf(fmaf(di, acc.x + selfv.x, b4.x), 0.f);
      r.y = fmaxf(fmaf(di, acc.y + selfv.y, b4.y), 0.f);
      r.z = fmaxf(fmaf(di, acc.z + selfv.z, b4.z), 0.f);
      r.w = fmaxf(fmaf(di, acc.w + selfv.w, b4.w), 0.f);
    }
    *(float4*)&a_sh[g * LDP + (fg << 2)] = r;
  }
  __syncthreads();

  // ---- mm phase: wave computes output cols wave*16..wave*16+15 ----
  int lane = tid & 63;
  int wave = tid >> 6;
  int col = lane & 15, quad = lane >> 4;
  const float* arow = &a_sh[col * LDP + (quad << 3)];
  float4 a0 = *(const float4*)(arow);
  float4 a1 = *(const float4*)(arow + 4);
  float4 a2 = *(const float4*)(arow + 32);
  float4 a3 = *(const float4*)(arow + 36);
  bf16x8 ah[2], al[2];
  split8(a0, a1, ah[0], al[0]);
  split8(a2, a3, ah[1], al[1]);

  bf16x8 wh[2], wl[2];
#pragma unroll
  for (int q = 0; q < 2; ++q) {
    wh[q] = Wp1[((wave * 2 + q) * 2) * 64 + lane];
    wl[q] = Wp1[((wave * 2 + q) * 2 + 1) * 64 + lane];
  }
  f32x4 acc1 = (f32x4){0.f, 0.f, 0.f, 0.f};
#pragma unroll
  for (int q = 0; q < 2; ++q) {
    acc1 = __builtin_amdgcn_mfma_f32_16x16x32_bf16(ah[q], wh[q], acc1, 0, 0, 0);
    acc1 = __builtin_amdgcn_mfma_f32_16x16x32_bf16(ah[q], wl[q], acc1, 0, 0, 0);
    acc1 = __builtin_amdgcn_mfma_f32_16x16x32_bf16(al[q], wh[q], acc1, 0, 0, 0);
  }

  if constexpr (!HEAD) {
#pragma unroll
    for (int r = 0; r < 4; ++r) {
      int row = row0 + (quad << 2) + r;
      if (row < n) {
        ((unsigned short*)out)[(size_t)row * 64 + wave * 16 + col] =
            f2bf_rne(acc1[r] * dinv[row]);
      }
    }
  } else {
    // h4 = relu(acc1 + b1) -> a_sh (reused; all reads of a above are done
    // only after the barrier below)
    float bv1 = b1p[wave * 16 + col];
    __syncthreads();  // everyone finished reading a_sh
#pragma unroll
    for (int r = 0; r < 4; ++r) {
      a_sh[((quad << 2) + r) * LDP + wave * 16 + col] = fmaxf(acc1[r] + bv1, 0.f);
    }
    __syncthreads();
    const float* hrow = &a_sh[col * LDP + (quad << 3)];
    float4 h0 = *(const float4*)(hrow);
    float4 h1 = *(const float4*)(hrow + 4);
    float4 h2 = *(const float4*)(hrow + 32);
    float4 h3 = *(const float4*)(hrow + 36);
    bf16x8 ah2[2], al2[2];
    split8(h0, h1, ah2[0], al2[0]);
    split8(h2, h3, ah2[1], al2[1]);
    bf16x8 wh2[2], wl2[2];
#pragma unroll
    for (int q = 0; q < 2; ++q) {
      wh2[q] = Wp2[((wave * 2 + q) * 2) * 64 + lane];
      wl2[q] = Wp2[((wave * 2 + q) * 2 + 1) * 64 + lane];
    }
    f32x4 acc2 = (f32x4){0.f, 0.f, 0.f, 0.f};
#pragma unroll
    for (int q = 0; q < 2; ++q) {
      acc2 = __builtin_amdgcn_mfma_f32_16x16x32_bf16(ah2[q], wh2[q], acc2, 0, 0, 0);
      acc2 = __builtin_amdgcn_mfma_f32_16x16x32_bf16(ah2[q], wl2[q], acc2, 0, 0, 0);
      acc2 = __builtin_amdgcn_mfma_f32_16x16x32_bf16(al2[q], wh2[q], acc2, 0, 0, 0);
    }
    float bv2 = b2p[wave * 16 + col];
#pragma unroll
    for (int r = 0; r < 4; ++r) {
      int row = row0 + (quad << 2) + r;
      if (row < n) {
        ((float*)out)[(size_t)row * 64 + wave * 16 + col] = acc2[r] + bv2;
      }
    }
  }
}

extern "C" void kernel_launch(void* const* d_in, const int* in_sizes, int n_in,
                              void* d_out, int out_size, void* d_ws, size_t ws_size,
                              hipStream_t stream) {
  const float* x = (const float*)d_in[0];
  const int* ei = (const int*)d_in[1];  // int32 per harness convention
  const float* W1 = (const float*)d_in[2];
  const float* b1 = (const float*)d_in[3];
  const float* W2 = (const float*)d_in[4];
  const float* b2 = (const float*)d_in[5];
  const float* W3 = (const float*)d_in[6];
  const float* b3 = (const float*)d_in[7];
  const float* fw1 = (const float*)d_in[8];
  const float* fb1 = (const float*)d_in[9];
  const float* fw2 = (const float*)d_in[10];
  const float* fb2 = (const float*)d_in[11];
  float* out = (float*)d_out;

  const int N = in_sizes[0] / 64;
  const int E = in_sizes[1] / 2;
  const int K = CDIV(N, BKT_NODES);  // buckets (98 for N=100k)

  // workspace (~31 MB)
  char* w = (char*)d_ws;
  auto take = [&](size_t bytes) -> char* {
    char* p = w;
    w += (bytes + 255) & ~(size_t)255;
    return p;
  };
  float* dinv = (float*)take((size_t)N * 4);
  int* row_ptr = (int*)take((size_t)(N + 1) * 4);
  int* bcnt = (int*)take((size_t)128 * 4);
  int* srcs = (int*)take((size_t)E * 4);
  bf16x8* wpack = (bf16x8*)take((size_t)5 * 1024 * 16);                    // 80 KB
  unsigned short* hwsA = (unsigned short*)take((size_t)(N + 1) * 64 * 2);  // 12.8 MB (+zero row)
  unsigned short* hwsB = (unsigned short*)take((size_t)(N + 1) * 64 * 2);  // 12.8 MB
  int2* pairs = (int2*)hwsA;  // 10.4 MB alias; consumed before k_mm writes hwsA

  const int B = 256;

  // ---- weight prep (+bcnt zero) + CSR build (atomic-free) ----
  k_prep<<<6, 512, 0, stream>>>(W1, W2, W3, fw1, fw2, wpack, bcnt);
  k_bucket<<<1024, B, 0, stream>>>(ei, bcnt, pairs, E);
  k_build<<<K, 1024, 0, stream>>>(pairs, bcnt, row_ptr, dinv, srcs, N, E, K);

  const int ntiles = CDIV(N, 16);
  const int MMG = CDIV(ntiles, 4);  // k_mm: 1 tile/wave, 4 waves/block

  // hws1 = bf16((x@W1)*dinv)
  k_mm<<<MMG, B, 0, stream>>>(x, wpack + 0 * 1024, dinv, hwsA, N);
  // h1 = relu(dinv*(agg+self)+b1); hws2 = bf16((h1@W2)*dinv)
  k_agg_mm<false><<<ntiles, B, 0, stream>>>(hwsA, dinv, row_ptr, srcs, b1,
                                            wpack + 1 * 1024, nullptr, nullptr, nullptr,
                                            hwsB, N);
  // h2; hws3 = bf16((h2@W3)*dinv)
  k_agg_mm<false><<<ntiles, B, 0, stream>>>(hwsB, dinv, row_ptr, srcs, b2,
                                            wpack + 2 * 1024, nullptr, nullptr, nullptr,
                                            hwsA, N);
  // h3; h4 = relu(h3@fw1+fb1); out = h4@fw2+fb2 (fp32)
  k_agg_mm<true><<<ntiles, B, 0, stream>>>(hwsA, dinv, row_ptr, srcs, b3,
                                           wpack + 3 * 1024, fb1, wpack + 4 * 1024, fb2,
                                           out, N);
}

// Round 7
// 253.518 us; speedup vs baseline: 1.0699x; 1.0257x over previous
//
#include <hip/hip_runtime.h>
#include <cstdint>
#include <cstddef>

// GCN link prediction: 3x GCNConv(64->64) + ReLU, then 2-layer MLP head.
// N=100k, E=1M, dims 64. Round 16:
//  - agg: 16-deep FIRST batch (one latency round covers deg<=16, 97% of
//    nodes) + rare 8-deep tail. The mm phase waits on the block's max-degree
//    node (E[max over 16 nodes] ~ 18 => 3 serialized rounds at 8-deep; now
//    1-2). Dropped the srcs software-pipeline (r13/r15 proved it null --
//    agg is MSHR-throughput bound, not index-latency bound).
//  - k_build: 512-node buckets -> 196 blocks (77% CU util, was 98/38%).
//  - kept: zero-row masked gathers, 16-lane groups, a_sh reuse in HEAD,
//    k_bucket<<<1024>>>, prep-folded bcnt zero.
//  - top-5 fillBufferAligned = harness 256MiB ws poison, untouchable.

#define CDIV(a, b) (((a) + (b) - 1) / (b))

typedef __attribute__((ext_vector_type(8))) short bf16x8;
typedef __attribute__((ext_vector_type(4))) float f32x4;

static constexpr int BKT_SHIFT = 9;             // 512 nodes per bucket
static constexpr int BKT_NODES = 1 << BKT_SHIFT;
static constexpr int BKT_CAP = 7424;            // mean 5120 + ~32 sigma

// Split a into hi (RNE bf16) + lo (truncated bf16 of exact residual).
__device__ __forceinline__ void split_bf(float a, short& hi, short& lo) {
  unsigned u = __float_as_uint(a);
  unsigned r = u + (0x7FFF + ((u >> 16) & 1));  // RNE round to bf16
  hi = (short)(r >> 16);
  float hirec = __uint_as_float(r & 0xFFFF0000u);
  float res = a - hirec;  // exact
  lo = (short)(__float_as_uint(res) >> 16);  // truncate
}

__device__ __forceinline__ unsigned short f2bf_rne(float a) {
  unsigned u = __float_as_uint(a);
  u += 0x7FFF + ((u >> 16) & 1);
  return (unsigned short)(u >> 16);
}

__device__ __forceinline__ float4 bf4_to_f4(uint2 u) {
  float4 v;
  v.x = __uint_as_float(u.x << 16);
  v.y = __uint_as_float(u.x & 0xFFFF0000u);
  v.z = __uint_as_float(u.y << 16);
  v.w = __uint_as_float(u.y & 0xFFFF0000u);
  return v;
}

// Pack two float4s (k 0..7 of a row) into hi/lo bf16x8 fragments.
__device__ __forceinline__ void split8(float4 x, float4 y, bf16x8& h, bf16x8& l) {
  float av[8] = {x.x, x.y, x.z, x.w, y.x, y.y, y.z, y.w};
#pragma unroll
  for (int j = 0; j < 8; ++j) {
    short hi, lo;
    split_bf(av[j], hi, lo);
    h[j] = hi;
    l[j] = lo;
  }
}

__device__ __forceinline__ float4 nt_ld4(const float* p) {
  f32x4 v = __builtin_nontemporal_load(reinterpret_cast<const f32x4*>(p));
  float4 r;
  r.x = v[0]; r.y = v[1]; r.z = v[2]; r.w = v[3];
  return r;
}

// Phase 1: partition edges into dst-range buckets (bucket = dst >> 9).
// Per block: LDS histogram of its chunk, one global atomicAdd per non-empty
// bucket to reserve a contiguous run, then write (s,d) pairs into the run.
__global__ __launch_bounds__(256)
void k_bucket(const int* __restrict__ ei, int* __restrict__ bcnt,
              int2* __restrict__ pairs, int E) {
  __shared__ int hist[256], rbase[256], roff[256];
  int t = threadIdx.x;
  int chunk = (E + gridDim.x - 1) / gridDim.x;
  int e0 = blockIdx.x * chunk;
  int e1 = min(e0 + chunk, E);
  hist[t] = 0;
  __syncthreads();
  for (int e = e0 + t; e < e1; e += 256) {
    int d = __builtin_nontemporal_load(&ei[E + e]);
    atomicAdd(&hist[d >> BKT_SHIFT], 1);
  }
  __syncthreads();
  roff[t] = 0;
  rbase[t] = hist[t] ? atomicAdd(&bcnt[t], hist[t]) : 0;
  __syncthreads();
  for (int e = e0 + t; e < e1; e += 256) {
    int d = __builtin_nontemporal_load(&ei[E + e]);
    int s = __builtin_nontemporal_load(&ei[e]);
    int b = d >> BKT_SHIFT;
    int r = atomicAdd(&roff[b], 1);
    int idx = rbase[b] + r;
    if (idx < BKT_CAP) pairs[(size_t)b * BKT_CAP + idx] = make_int2(s, d);
  }
}

// Phase 2: one block per bucket. LDS histogram over the bucket's <=512 dsts,
// Blelloch exclusive scan, emit row_ptr slice + dinv, then scatter srcs via
// LDS cursors. No global atomics.
__global__ __launch_bounds__(1024)
void k_build(const int2* __restrict__ pairs, const int* __restrict__ bcnt,
             int* __restrict__ row_ptr, float* __restrict__ dinv,
             int* __restrict__ srcs, int N, int E, int K) {
  __shared__ int cnt[BKT_NODES];
  __shared__ int deg[BKT_NODES];
  __shared__ int ebase_sh;
  int b = blockIdx.x;
  int t = threadIdx.x;
  int lo = b << BKT_SHIFT;
  int range = min(BKT_NODES, N - lo);
  int sz = min(bcnt[b], BKT_CAP);
  if (t == 0) {
    int s = 0;
    for (int i = 0; i < b; ++i) s += bcnt[i];
    ebase_sh = s;
  }
  if (t < BKT_NODES) cnt[t] = 0;
  __syncthreads();
  int ebase = ebase_sh;
  const int2* pb = pairs + (size_t)b * BKT_CAP;
  for (int i = t; i < sz; i += 1024) {
    atomicAdd(&cnt[pb[i].y - lo], 1);
  }
  __syncthreads();
  if (t < BKT_NODES) deg[t] = cnt[t];
  __syncthreads();
  // Blelloch exclusive scan over cnt[0..512)
  int offset = 1;
  for (int d2 = BKT_NODES / 2; d2 > 0; d2 >>= 1) {
    if (t < d2) {
      int ai = offset * (2 * t + 1) - 1;
      int bi = offset * (2 * t + 2) - 1;
      cnt[bi] += cnt[ai];
    }
    offset <<= 1;
    __syncthreads();
  }
  if (t == 0) cnt[BKT_NODES - 1] = 0;
  __syncthreads();
  for (int d2 = 1; d2 < BKT_NODES; d2 <<= 1) {
    offset >>= 1;
    if (t < d2) {
      int ai = offset * (2 * t + 1) - 1;
      int bi = offset * (2 * t + 2) - 1;
      int tmp = cnt[ai];
      cnt[ai] = cnt[bi];
      cnt[bi] += tmp;
    }
    __syncthreads();
  }
  // row_ptr + dinv (reads cnt; must complete before fill mutates cnt)
  if (t < range) {
    row_ptr[lo + t] = ebase + cnt[t];
    dinv[lo + t] = rsqrtf((float)deg[t] + 1.0f);
  }
  if (b == K - 1 && t == 0) row_ptr[N] = E;
  __syncthreads();
  // scatter srcs via LDS cursors
  for (int i = t; i < sz; i += 1024) {
    int2 p = pb[i];
    int pos = ebase + atomicAdd(&cnt[p.y - lo], 1);
    srcs[pos] = p.x;
  }
}

// Pre-split 5 weight matrices (64x64, [in,out] row-major) into hi/lo bf16
// fragments, packed: packed[mat*1024 + ((t*2+q)*2+h)*64 + lane].
// Block 5 zeroes bcnt (folded k_zero launch).
__global__ void k_prep(const float* __restrict__ w0, const float* __restrict__ w1,
                       const float* __restrict__ w2, const float* __restrict__ w3,
                       const float* __restrict__ w4, bf16x8* __restrict__ packed,
                       int* __restrict__ bcnt) {
  if (blockIdx.x == 5) {
    if (threadIdx.x < 256) bcnt[threadIdx.x] = 0;
    return;
  }
  const float* W;
  switch (blockIdx.x) {
    case 0: W = w0; break;
    case 1: W = w1; break;
    case 2: W = w2; break;
    case 3: W = w3; break;
    default: W = w4; break;
  }
  int tid = threadIdx.x;  // 0..511
  int lane = tid & 63;
  int q = (tid >> 6) & 1;
  int t = tid >> 7;
  int col = lane & 15, quad = lane >> 4;
  bf16x8 hi8, lo8;
#pragma unroll
  for (int j = 0; j < 8; ++j) {
    int k = q * 32 + quad * 8 + j;
    short hi, lo;
    split_bf(W[k * 64 + t * 16 + col], hi, lo);
    hi8[j] = hi;
    lo8[j] = lo;
  }
  size_t base = (size_t)blockIdx.x * 1024 + ((t * 2 + q) * 2) * 64 + lane;
  packed[base] = hi8;
  packed[base + 64] = lo8;
}

// C[n x 64] = A @ W (*dinv[row]), bf16 out (gather-table producer; row n of
// out zeroed by block 0 -- the shared "masked gather" target). One 16-row
// tile per wave. A input is read-once -> non-temporal loads.
// Verified layouts: A[m=lane&15][k=quad*8+j]; B[k][n=lane&15];
// C col=lane&15, row=quad*4+reg.
__global__ __launch_bounds__(256, 4)
void k_mm(const float* __restrict__ in, const bf16x8* __restrict__ Wp,
          const float* __restrict__ dinv, unsigned short* __restrict__ out, int n) {
  if (blockIdx.x == 0 && threadIdx.x < 32) {
    ((unsigned int*)out)[(size_t)n * 32 + threadIdx.x] = 0u;  // zero row n
  }
  int lane = threadIdx.x & 63;
  int col = lane & 15, quad = lane >> 4;
  int tile = (blockIdx.x * blockDim.x + threadIdx.x) >> 6;
  int ntiles = (n + 15) >> 4;
  if (tile >= ntiles) return;

  bf16x8 wh[4][2], wl[4][2];
#pragma unroll
  for (int t = 0; t < 4; ++t)
#pragma unroll
    for (int q = 0; q < 2; ++q) {
      wh[t][q] = Wp[((t * 2 + q) * 2) * 64 + lane];
      wl[t][q] = Wp[((t * 2 + q) * 2 + 1) * 64 + lane];
    }

  int row0 = tile << 4;
  int ar = row0 + col;
  if (ar > n - 1) ar = n - 1;  // clamp; stores guarded
  const float* arow = in + (size_t)ar * 64 + quad * 8;
  float4 a0 = nt_ld4(arow), a1 = nt_ld4(arow + 4);
  float4 a2 = nt_ld4(arow + 32), a3 = nt_ld4(arow + 36);

  bf16x8 ah[2], al[2];
  split8(a0, a1, ah[0], al[0]);
  split8(a2, a3, ah[1], al[1]);

  f32x4 acc[4];
#pragma unroll
  for (int t = 0; t < 4; ++t) acc[t] = (f32x4){0.f, 0.f, 0.f, 0.f};
#pragma unroll
  for (int t = 0; t < 4; ++t)
#pragma unroll
    for (int q = 0; q < 2; ++q) {
      acc[t] = __builtin_amdgcn_mfma_f32_16x16x32_bf16(ah[q], wh[t][q], acc[t], 0, 0, 0);
      acc[t] = __builtin_amdgcn_mfma_f32_16x16x32_bf16(ah[q], wl[t][q], acc[t], 0, 0, 0);
      acc[t] = __builtin_amdgcn_mfma_f32_16x16x32_bf16(al[q], wh[t][q], acc[t], 0, 0, 0);
    }
  float dv[4];
#pragma unroll
  for (int r = 0; r < 4; ++r) {
    int row = row0 + quad * 4 + r;
    dv[r] = (row < n) ? dinv[row] : 0.0f;
  }
#pragma unroll
  for (int t = 0; t < 4; ++t)
#pragma unroll
    for (int r = 0; r < 4; ++r) {
      int row = row0 + quad * 4 + r;
      if (row < n) out[(size_t)row * 64 + t * 16 + col] = f2bf_rne(acc[t][r] * dv[r]);
    }
}

// Fused aggregate + mm. Block = 256 threads = 16 nodes (one mm tile).
// Agg: lane-group g (16 lanes) owns node row0+g; lane fg owns 8B (4 bf16) of
// the 128B row. 16-deep first batch (one latency round covers deg<=16, 97%
// of nodes; block critical path = max-degree node), rare 8-deep tail loop.
// Masked slots gather the all-zero row n (one L1-hot line), adds are
// unconditional. No cross-lane reduction.
// MM: each wave computes one 16-col stripe of the 16x64 split-bf16 mm.
//   HEAD=false: out = bf16((a@Wp1)*dinv[row]) (next hws table; zeroes row n)
//   HEAD=true:  h4 = relu(a@Wp1+b1p) -> a_sh (reused); out = fp32(h4@Wp2+b2p)
template <bool HEAD>
__global__ __launch_bounds__(256, 4)
void k_agg_mm(const unsigned short* __restrict__ hws, const float* __restrict__ dinv,
              const int* __restrict__ row_ptr, const int* __restrict__ srcs,
              const float* __restrict__ bagg,
              const bf16x8* __restrict__ Wp1, const float* __restrict__ b1p,
              const bf16x8* __restrict__ Wp2, const float* __restrict__ b2p,
              void* __restrict__ out, int n) {
  constexpr int LDP = 68;  // fp32 row pad: 16B-aligned float4s, ~2-way banks
  __shared__ float a_sh[16 * LDP];
  int tid = threadIdx.x;
  int g = tid >> 4;    // node group 0..15
  int fg = tid & 15;   // 4-bf16 feature group
  int row0 = blockIdx.x << 4;
  const uint2* hw2 = (const uint2*)hws;  // row = 16 x uint2

  if (!HEAD && blockIdx.x == 0 && tid < 32) {
    ((unsigned int*)out)[(size_t)n * 32 + tid] = 0u;  // zero row n of next table
  }

  int node = row0 + g;
  bool valid = node < n;
  int nd = valid ? node : n;             // invalid -> zero row
  uint2 su = hw2[(size_t)nd * 16 + fg];  // self row gather, issued early
  float di = valid ? dinv[node] : 0.f;
  int p0 = 0, p1 = 0;
  if (valid) {
    p0 = row_ptr[node];
    p1 = row_ptr[node + 1];
  }
  float4 acc = make_float4(0.f, 0.f, 0.f, 0.f);
  if (p0 < p1) {
    // 16-deep first batch: covers deg<=16 in ONE latency round
    int s[16];
#pragma unroll
    for (int j = 0; j < 16; ++j) {
      int ij = p0 + j;
      bool ok = ij < p1;
      int sv = __builtin_nontemporal_load(&srcs[ok ? ij : p1 - 1]);
      s[j] = ok ? sv : n;  // masked -> zero row
    }
    uint2 u[16];
#pragma unroll
    for (int j = 0; j < 16; ++j) u[j] = hw2[(size_t)s[j] * 16 + fg];
#pragma unroll
    for (int j = 0; j < 16; ++j) {
      float4 v = bf4_to_f4(u[j]);
      acc.x += v.x;
      acc.y += v.y;
      acc.z += v.z;
      acc.w += v.w;
    }
    // rare tail (deg > 16): simple 8-deep batches
    for (int p = p0 + 16; p < p1; p += 8) {
      int s2[8];
#pragma unroll
      for (int j = 0; j < 8; ++j) {
        int ij = p + j;
        bool ok = ij < p1;
        int sv = __builtin_nontemporal_load(&srcs[ok ? ij : p1 - 1]);
        s2[j] = ok ? sv : n;
      }
      uint2 u2[8];
#pragma unroll
      for (int j = 0; j < 8; ++j) u2[j] = hw2[(size_t)s2[j] * 16 + fg];
#pragma unroll
      for (int j = 0; j < 8; ++j) {
        float4 v = bf4_to_f4(u2[j]);
        acc.x += v.x;
        acc.y += v.y;
        acc.z += v.z;
        acc.w += v.w;
      }
    }
  }
  {
    float4 selfv = bf4_to_f4(su);
    float4 b4 = ((const float4*)bagg)[fg];
    float4 r = make_float4(0.f, 0.f, 0.f, 0.f);
    if (valid) {
      r.x = fmaxf(fmaf(di, acc.x + selfv.x, b4.x), 0.f);
      r.y = fmaxf(fmaf(di, acc.y + selfv.y, b4.y), 0.f);
      r.z = fmaxf(fmaf(di, acc.z + selfv.z, b4.z), 0.f);
      r.w = fmaxf(fmaf(di, acc.w + selfv.w, b4.w), 0.f);
    }
    *(float4*)&a_sh[g * LDP + (fg << 2)] = r;
  }
  __syncthreads();

  // ---- mm phase: wave computes output cols wave*16..wave*16+15 ----
  int lane = tid & 63;
  int wave = tid >> 6;
  int col = lane & 15, quad = lane >> 4;
  const float* arow = &a_sh[col * LDP + (quad << 3)];
  float4 a0 = *(const float4*)(arow);
  float4 a1 = *(const float4*)(arow + 4);
  float4 a2 = *(const float4*)(arow + 32);
  float4 a3 = *(const float4*)(arow + 36);
  bf16x8 ah[2], al[2];
  split8(a0, a1, ah[0], al[0]);
  split8(a2, a3, ah[1], al[1]);

  bf16x8 wh[2], wl[2];
#pragma unroll
  for (int q = 0; q < 2; ++q) {
    wh[q] = Wp1[((wave * 2 + q) * 2) * 64 + lane];
    wl[q] = Wp1[((wave * 2 + q) * 2 + 1) * 64 + lane];
  }
  f32x4 acc1 = (f32x4){0.f, 0.f, 0.f, 0.f};
#pragma unroll
  for (int q = 0; q < 2; ++q) {
    acc1 = __builtin_amdgcn_mfma_f32_16x16x32_bf16(ah[q], wh[q], acc1, 0, 0, 0);
    acc1 = __builtin_amdgcn_mfma_f32_16x16x32_bf16(ah[q], wl[q], acc1, 0, 0, 0);
    acc1 = __builtin_amdgcn_mfma_f32_16x16x32_bf16(al[q], wh[q], acc1, 0, 0, 0);
  }

  if constexpr (!HEAD) {
#pragma unroll
    for (int r = 0; r < 4; ++r) {
      int row = row0 + (quad << 2) + r;
      if (row < n) {
        ((unsigned short*)out)[(size_t)row * 64 + wave * 16 + col] =
            f2bf_rne(acc1[r] * dinv[row]);
      }
    }
  } else {
    // h4 = relu(acc1 + b1) -> a_sh (reused; all reads of a above are done
    // only after the barrier below)
    float bv1 = b1p[wave * 16 + col];
    __syncthreads();  // everyone finished reading a_sh
#pragma unroll
    for (int r = 0; r < 4; ++r) {
      a_sh[((quad << 2) + r) * LDP + wave * 16 + col] = fmaxf(acc1[r] + bv1, 0.f);
    }
    __syncthreads();
    const float* hrow = &a_sh[col * LDP + (quad << 3)];
    float4 h0 = *(const float4*)(hrow);
    float4 h1 = *(const float4*)(hrow + 4);
    float4 h2 = *(const float4*)(hrow + 32);
    float4 h3 = *(const float4*)(hrow + 36);
    bf16x8 ah2[2], al2[2];
    split8(h0, h1, ah2[0], al2[0]);
    split8(h2, h3, ah2[1], al2[1]);
    bf16x8 wh2[2], wl2[2];
#pragma unroll
    for (int q = 0; q < 2; ++q) {
      wh2[q] = Wp2[((wave * 2 + q) * 2) * 64 + lane];
      wl2[q] = Wp2[((wave * 2 + q) * 2 + 1) * 64 + lane];
    }
    f32x4 acc2 = (f32x4){0.f, 0.f, 0.f, 0.f};
#pragma unroll
    for (int q = 0; q < 2; ++q) {
      acc2 = __builtin_amdgcn_mfma_f32_16x16x32_bf16(ah2[q], wh2[q], acc2, 0, 0, 0);
      acc2 = __builtin_amdgcn_mfma_f32_16x16x32_bf16(ah2[q], wl2[q], acc2, 0, 0, 0);
      acc2 = __builtin_amdgcn_mfma_f32_16x16x32_bf16(al2[q], wh2[q], acc2, 0, 0, 0);
    }
    float bv2 = b2p[wave * 16 + col];
#pragma unroll
    for (int r = 0; r < 4; ++r) {
      int row = row0 + (quad << 2) + r;
      if (row < n) {
        ((float*)out)[(size_t)row * 64 + wave * 16 + col] = acc2[r] + bv2;
      }
    }
  }
}

extern "C" void kernel_launch(void* const* d_in, const int* in_sizes, int n_in,
                              void* d_out, int out_size, void* d_ws, size_t ws_size,
                              hipStream_t stream) {
  const float* x = (const float*)d_in[0];
  const int* ei = (const int*)d_in[1];  // int32 per harness convention
  const float* W1 = (const float*)d_in[2];
  const float* b1 = (const float*)d_in[3];
  const float* W2 = (const float*)d_in[4];
  const float* b2 = (const float*)d_in[5];
  const float* W3 = (const float*)d_in[6];
  const float* b3 = (const float*)d_in[7];
  const float* fw1 = (const float*)d_in[8];
  const float* fb1 = (const float*)d_in[9];
  const float* fw2 = (const float*)d_in[10];
  const float* fb2 = (const float*)d_in[11];
  float* out = (float*)d_out;

  const int N = in_sizes[0] / 64;
  const int E = in_sizes[1] / 2;
  const int K = CDIV(N, BKT_NODES);  // buckets (196 for N=100k)

  // workspace (~31 MB)
  char* w = (char*)d_ws;
  auto take = [&](size_t bytes) -> char* {
    char* p = w;
    w += (bytes + 255) & ~(size_t)255;
    return p;
  };
  float* dinv = (float*)take((size_t)N * 4);
  int* row_ptr = (int*)take((size_t)(N + 1) * 4);
  int* bcnt = (int*)take((size_t)256 * 4);
  int* srcs = (int*)take((size_t)E * 4);
  bf16x8* wpack = (bf16x8*)take((size_t)5 * 1024 * 16);                    // 80 KB
  unsigned short* hwsA = (unsigned short*)take((size_t)(N + 1) * 64 * 2);  // 12.8 MB (+zero row)
  unsigned short* hwsB = (unsigned short*)take((size_t)(N + 1) * 64 * 2);  // 12.8 MB
  int2* pairs = (int2*)hwsA;  // 11.6 MB alias; consumed before k_mm writes hwsA

  const int B = 256;

  // ---- weight prep (+bcnt zero) + CSR build (atomic-free) ----
  k_prep<<<6, 512, 0, stream>>>(W1, W2, W3, fw1, fw2, wpack, bcnt);
  k_bucket<<<1024, B, 0, stream>>>(ei, bcnt, pairs, E);
  k_build<<<K, 1024, 0, stream>>>(pairs, bcnt, row_ptr, dinv, srcs, N, E, K);

  const int ntiles = CDIV(N, 16);
  const int MMG = CDIV(ntiles, 4);  // k_mm: 1 tile/wave, 4 waves/block

  // hws1 = bf16((x@W1)*dinv)
  k_mm<<<MMG, B, 0, stream>>>(x, wpack + 0 * 1024, dinv, hwsA, N);
  // h1 = relu(dinv*(agg+self)+b1); hws2 = bf16((h1@W2)*dinv)
  k_agg_mm<false><<<ntiles, B, 0, stream>>>(hwsA, dinv, row_ptr, srcs, b1,
                                            wpack + 1 * 1024, nullptr, nullptr, nullptr,
                                            hwsB, N);
  // h2; hws3 = bf16((h2@W3)*dinv)
  k_agg_mm<false><<<ntiles, B, 0, stream>>>(hwsB, dinv, row_ptr, srcs, b2,
                                            wpack + 2 * 1024, nullptr, nullptr, nullptr,
                                            hwsA, N);
  // h3; h4 = relu(h3@fw1+fb1); out = h4@fw2+fb2 (fp32)
  k_agg_mm<true><<<ntiles, B, 0, stream>>>(hwsA, dinv, row_ptr, srcs, b3,
                                           wpack + 3 * 1024, fb1, wpack + 4 * 1024, fb2,
                                           out, N);
}

// Round 8
// 243.637 us; speedup vs baseline: 1.1133x; 1.0406x over previous
//
#include <hip/hip_runtime.h>
#include <cstdint>
#include <cstddef>

// GCN link prediction: 3x GCNConv(64->64) + ReLU, then 2-layer MLP head.
// N=100k, E=1M, dims 64. Round 17:
//  - k_agg_mm: __launch_bounds__(256, 6) (was 4). Agg is MSHR-bound
//    (r13-r16: pattern changes null, 16-deep batch +6.5us); outstanding
//    misses scale with resident waves -> 16 -> 24 waves/CU. VGPR budget at
//    6 waves/SIMD is ~85; the 16-deep batch needs ~70-75. (8 waves needs
//    <=64 -> would spill; not attempted.)
//  - k_bucket: grid 1024 -> 512. At 1024, per-(block,bucket) runs are ~5
//    pairs (40B) -> ~3 blocks share each 128B pairs line -> cross-XCD RMW
//    writebacks (self-inflicted r8 disease). 512 doubles run length.
//  - everything else unchanged from r16.

#define CDIV(a, b) (((a) + (b) - 1) / (b))

typedef __attribute__((ext_vector_type(8))) short bf16x8;
typedef __attribute__((ext_vector_type(4))) float f32x4;

static constexpr int BKT_SHIFT = 9;             // 512 nodes per bucket
static constexpr int BKT_NODES = 1 << BKT_SHIFT;
static constexpr int BKT_CAP = 7424;            // mean 5120 + ~32 sigma

// Split a into hi (RNE bf16) + lo (truncated bf16 of exact residual).
__device__ __forceinline__ void split_bf(float a, short& hi, short& lo) {
  unsigned u = __float_as_uint(a);
  unsigned r = u + (0x7FFF + ((u >> 16) & 1));  // RNE round to bf16
  hi = (short)(r >> 16);
  float hirec = __uint_as_float(r & 0xFFFF0000u);
  float res = a - hirec;  // exact
  lo = (short)(__float_as_uint(res) >> 16);  // truncate
}

__device__ __forceinline__ unsigned short f2bf_rne(float a) {
  unsigned u = __float_as_uint(a);
  u += 0x7FFF + ((u >> 16) & 1);
  return (unsigned short)(u >> 16);
}

__device__ __forceinline__ float4 bf4_to_f4(uint2 u) {
  float4 v;
  v.x = __uint_as_float(u.x << 16);
  v.y = __uint_as_float(u.x & 0xFFFF0000u);
  v.z = __uint_as_float(u.y << 16);
  v.w = __uint_as_float(u.y & 0xFFFF0000u);
  return v;
}

// Pack two float4s (k 0..7 of a row) into hi/lo bf16x8 fragments.
__device__ __forceinline__ void split8(float4 x, float4 y, bf16x8& h, bf16x8& l) {
  float av[8] = {x.x, x.y, x.z, x.w, y.x, y.y, y.z, y.w};
#pragma unroll
  for (int j = 0; j < 8; ++j) {
    short hi, lo;
    split_bf(av[j], hi, lo);
    h[j] = hi;
    l[j] = lo;
  }
}

__device__ __forceinline__ float4 nt_ld4(const float* p) {
  f32x4 v = __builtin_nontemporal_load(reinterpret_cast<const f32x4*>(p));
  float4 r;
  r.x = v[0]; r.y = v[1]; r.z = v[2]; r.w = v[3];
  return r;
}

// Phase 1: partition edges into dst-range buckets (bucket = dst >> 9).
// Per block: LDS histogram of its chunk, one global atomicAdd per non-empty
// bucket to reserve a contiguous run, then write (s,d) pairs into the run.
__global__ __launch_bounds__(256)
void k_bucket(const int* __restrict__ ei, int* __restrict__ bcnt,
              int2* __restrict__ pairs, int E) {
  __shared__ int hist[256], rbase[256], roff[256];
  int t = threadIdx.x;
  int chunk = (E + gridDim.x - 1) / gridDim.x;
  int e0 = blockIdx.x * chunk;
  int e1 = min(e0 + chunk, E);
  hist[t] = 0;
  __syncthreads();
  for (int e = e0 + t; e < e1; e += 256) {
    int d = __builtin_nontemporal_load(&ei[E + e]);
    atomicAdd(&hist[d >> BKT_SHIFT], 1);
  }
  __syncthreads();
  roff[t] = 0;
  rbase[t] = hist[t] ? atomicAdd(&bcnt[t], hist[t]) : 0;
  __syncthreads();
  for (int e = e0 + t; e < e1; e += 256) {
    int d = __builtin_nontemporal_load(&ei[E + e]);
    int s = __builtin_nontemporal_load(&ei[e]);
    int b = d >> BKT_SHIFT;
    int r = atomicAdd(&roff[b], 1);
    int idx = rbase[b] + r;
    if (idx < BKT_CAP) pairs[(size_t)b * BKT_CAP + idx] = make_int2(s, d);
  }
}

// Phase 2: one block per bucket. LDS histogram over the bucket's <=512 dsts,
// Blelloch exclusive scan, emit row_ptr slice + dinv, then scatter srcs via
// LDS cursors. No global atomics.
__global__ __launch_bounds__(1024)
void k_build(const int2* __restrict__ pairs, const int* __restrict__ bcnt,
             int* __restrict__ row_ptr, float* __restrict__ dinv,
             int* __restrict__ srcs, int N, int E, int K) {
  __shared__ int cnt[BKT_NODES];
  __shared__ int deg[BKT_NODES];
  __shared__ int ebase_sh;
  int b = blockIdx.x;
  int t = threadIdx.x;
  int lo = b << BKT_SHIFT;
  int range = min(BKT_NODES, N - lo);
  int sz = min(bcnt[b], BKT_CAP);
  if (t == 0) {
    int s = 0;
    for (int i = 0; i < b; ++i) s += bcnt[i];
    ebase_sh = s;
  }
  if (t < BKT_NODES) cnt[t] = 0;
  __syncthreads();
  int ebase = ebase_sh;
  const int2* pb = pairs + (size_t)b * BKT_CAP;
  for (int i = t; i < sz; i += 1024) {
    atomicAdd(&cnt[pb[i].y - lo], 1);
  }
  __syncthreads();
  if (t < BKT_NODES) deg[t] = cnt[t];
  __syncthreads();
  // Blelloch exclusive scan over cnt[0..512)
  int offset = 1;
  for (int d2 = BKT_NODES / 2; d2 > 0; d2 >>= 1) {
    if (t < d2) {
      int ai = offset * (2 * t + 1) - 1;
      int bi = offset * (2 * t + 2) - 1;
      cnt[bi] += cnt[ai];
    }
    offset <<= 1;
    __syncthreads();
  }
  if (t == 0) cnt[BKT_NODES - 1] = 0;
  __syncthreads();
  for (int d2 = 1; d2 < BKT_NODES; d2 <<= 1) {
    offset >>= 1;
    if (t < d2) {
      int ai = offset * (2 * t + 1) - 1;
      int bi = offset * (2 * t + 2) - 1;
      int tmp = cnt[ai];
      cnt[ai] = cnt[bi];
      cnt[bi] += tmp;
    }
    __syncthreads();
  }
  // row_ptr + dinv (reads cnt; must complete before fill mutates cnt)
  if (t < range) {
    row_ptr[lo + t] = ebase + cnt[t];
    dinv[lo + t] = rsqrtf((float)deg[t] + 1.0f);
  }
  if (b == K - 1 && t == 0) row_ptr[N] = E;
  __syncthreads();
  // scatter srcs via LDS cursors
  for (int i = t; i < sz; i += 1024) {
    int2 p = pb[i];
    int pos = ebase + atomicAdd(&cnt[p.y - lo], 1);
    srcs[pos] = p.x;
  }
}

// Pre-split 5 weight matrices (64x64, [in,out] row-major) into hi/lo bf16
// fragments, packed: packed[mat*1024 + ((t*2+q)*2+h)*64 + lane].
// Block 5 zeroes bcnt (folded k_zero launch).
__global__ void k_prep(const float* __restrict__ w0, const float* __restrict__ w1,
                       const float* __restrict__ w2, const float* __restrict__ w3,
                       const float* __restrict__ w4, bf16x8* __restrict__ packed,
                       int* __restrict__ bcnt) {
  if (blockIdx.x == 5) {
    if (threadIdx.x < 256) bcnt[threadIdx.x] = 0;
    return;
  }
  const float* W;
  switch (blockIdx.x) {
    case 0: W = w0; break;
    case 1: W = w1; break;
    case 2: W = w2; break;
    case 3: W = w3; break;
    default: W = w4; break;
  }
  int tid = threadIdx.x;  // 0..511
  int lane = tid & 63;
  int q = (tid >> 6) & 1;
  int t = tid >> 7;
  int col = lane & 15, quad = lane >> 4;
  bf16x8 hi8, lo8;
#pragma unroll
  for (int j = 0; j < 8; ++j) {
    int k = q * 32 + quad * 8 + j;
    short hi, lo;
    split_bf(W[k * 64 + t * 16 + col], hi, lo);
    hi8[j] = hi;
    lo8[j] = lo;
  }
  size_t base = (size_t)blockIdx.x * 1024 + ((t * 2 + q) * 2) * 64 + lane;
  packed[base] = hi8;
  packed[base + 64] = lo8;
}

// C[n x 64] = A @ W (*dinv[row]), bf16 out (gather-table producer; row n of
// out zeroed by block 0 -- the shared "masked gather" target). One 16-row
// tile per wave. A input is read-once -> non-temporal loads.
// Verified layouts: A[m=lane&15][k=quad*8+j]; B[k][n=lane&15];
// C col=lane&15, row=quad*4+reg.
__global__ __launch_bounds__(256, 4)
void k_mm(const float* __restrict__ in, const bf16x8* __restrict__ Wp,
          const float* __restrict__ dinv, unsigned short* __restrict__ out, int n) {
  if (blockIdx.x == 0 && threadIdx.x < 32) {
    ((unsigned int*)out)[(size_t)n * 32 + threadIdx.x] = 0u;  // zero row n
  }
  int lane = threadIdx.x & 63;
  int col = lane & 15, quad = lane >> 4;
  int tile = (blockIdx.x * blockDim.x + threadIdx.x) >> 6;
  int ntiles = (n + 15) >> 4;
  if (tile >= ntiles) return;

  bf16x8 wh[4][2], wl[4][2];
#pragma unroll
  for (int t = 0; t < 4; ++t)
#pragma unroll
    for (int q = 0; q < 2; ++q) {
      wh[t][q] = Wp[((t * 2 + q) * 2) * 64 + lane];
      wl[t][q] = Wp[((t * 2 + q) * 2 + 1) * 64 + lane];
    }

  int row0 = tile << 4;
  int ar = row0 + col;
  if (ar > n - 1) ar = n - 1;  // clamp; stores guarded
  const float* arow = in + (size_t)ar * 64 + quad * 8;
  float4 a0 = nt_ld4(arow), a1 = nt_ld4(arow + 4);
  float4 a2 = nt_ld4(arow + 32), a3 = nt_ld4(arow + 36);

  bf16x8 ah[2], al[2];
  split8(a0, a1, ah[0], al[0]);
  split8(a2, a3, ah[1], al[1]);

  f32x4 acc[4];
#pragma unroll
  for (int t = 0; t < 4; ++t) acc[t] = (f32x4){0.f, 0.f, 0.f, 0.f};
#pragma unroll
  for (int t = 0; t < 4; ++t)
#pragma unroll
    for (int q = 0; q < 2; ++q) {
      acc[t] = __builtin_amdgcn_mfma_f32_16x16x32_bf16(ah[q], wh[t][q], acc[t], 0, 0, 0);
      acc[t] = __builtin_amdgcn_mfma_f32_16x16x32_bf16(ah[q], wl[t][q], acc[t], 0, 0, 0);
      acc[t] = __builtin_amdgcn_mfma_f32_16x16x32_bf16(al[q], wh[t][q], acc[t], 0, 0, 0);
    }
  float dv[4];
#pragma unroll
  for (int r = 0; r < 4; ++r) {
    int row = row0 + quad * 4 + r;
    dv[r] = (row < n) ? dinv[row] : 0.0f;
  }
#pragma unroll
  for (int t = 0; t < 4; ++t)
#pragma unroll
    for (int r = 0; r < 4; ++r) {
      int row = row0 + quad * 4 + r;
      if (row < n) out[(size_t)row * 64 + t * 16 + col] = f2bf_rne(acc[t][r] * dv[r]);
    }
}

// Fused aggregate + mm. Block = 256 threads = 16 nodes (one mm tile).
// Agg: lane-group g (16 lanes) owns node row0+g; lane fg owns 8B (4 bf16) of
// the 128B row. 16-deep first batch (one latency round covers deg<=16, 97%
// of nodes), rare 8-deep tail. Masked slots gather the all-zero row n (one
// L1-hot line), adds unconditional. launch_bounds(256,6): 24 waves/CU (was
// 16) -- agg is MSHR-bound, outstanding misses scale with resident waves.
// MM: each wave computes one 16-col stripe of the 16x64 split-bf16 mm.
//   HEAD=false: out = bf16((a@Wp1)*dinv[row]) (next hws table; zeroes row n)
//   HEAD=true:  h4 = relu(a@Wp1+b1p) -> a_sh (reused); out = fp32(h4@Wp2+b2p)
template <bool HEAD>
__global__ __launch_bounds__(256, 6)
void k_agg_mm(const unsigned short* __restrict__ hws, const float* __restrict__ dinv,
              const int* __restrict__ row_ptr, const int* __restrict__ srcs,
              const float* __restrict__ bagg,
              const bf16x8* __restrict__ Wp1, const float* __restrict__ b1p,
              const bf16x8* __restrict__ Wp2, const float* __restrict__ b2p,
              void* __restrict__ out, int n) {
  constexpr int LDP = 68;  // fp32 row pad: 16B-aligned float4s, ~2-way banks
  __shared__ float a_sh[16 * LDP];
  int tid = threadIdx.x;
  int g = tid >> 4;    // node group 0..15
  int fg = tid & 15;   // 4-bf16 feature group
  int row0 = blockIdx.x << 4;
  const uint2* hw2 = (const uint2*)hws;  // row = 16 x uint2

  if (!HEAD && blockIdx.x == 0 && tid < 32) {
    ((unsigned int*)out)[(size_t)n * 32 + tid] = 0u;  // zero row n of next table
  }

  int node = row0 + g;
  bool valid = node < n;
  int nd = valid ? node : n;             // invalid -> zero row
  uint2 su = hw2[(size_t)nd * 16 + fg];  // self row gather, issued early
  float di = valid ? dinv[node] : 0.f;
  int p0 = 0, p1 = 0;
  if (valid) {
    p0 = row_ptr[node];
    p1 = row_ptr[node + 1];
  }
  float4 acc = make_float4(0.f, 0.f, 0.f, 0.f);
  if (p0 < p1) {
    // 16-deep first batch: covers deg<=16 in ONE latency round
    int s[16];
#pragma unroll
    for (int j = 0; j < 16; ++j) {
      int ij = p0 + j;
      bool ok = ij < p1;
      int sv = __builtin_nontemporal_load(&srcs[ok ? ij : p1 - 1]);
      s[j] = ok ? sv : n;  // masked -> zero row
    }
    uint2 u[16];
#pragma unroll
    for (int j = 0; j < 16; ++j) u[j] = hw2[(size_t)s[j] * 16 + fg];
#pragma unroll
    for (int j = 0; j < 16; ++j) {
      float4 v = bf4_to_f4(u[j]);
      acc.x += v.x;
      acc.y += v.y;
      acc.z += v.z;
      acc.w += v.w;
    }
    // rare tail (deg > 16): simple 8-deep batches
    for (int p = p0 + 16; p < p1; p += 8) {
      int s2[8];
#pragma unroll
      for (int j = 0; j < 8; ++j) {
        int ij = p + j;
        bool ok = ij < p1;
        int sv = __builtin_nontemporal_load(&srcs[ok ? ij : p1 - 1]);
        s2[j] = ok ? sv : n;
      }
      uint2 u2[8];
#pragma unroll
      for (int j = 0; j < 8; ++j) u2[j] = hw2[(size_t)s2[j] * 16 + fg];
#pragma unroll
      for (int j = 0; j < 8; ++j) {
        float4 v = bf4_to_f4(u2[j]);
        acc.x += v.x;
        acc.y += v.y;
        acc.z += v.z;
        acc.w += v.w;
      }
    }
  }
  {
    float4 selfv = bf4_to_f4(su);
    float4 b4 = ((const float4*)bagg)[fg];
    float4 r = make_float4(0.f, 0.f, 0.f, 0.f);
    if (valid) {
      r.x = fmaxf(fmaf(di, acc.x + selfv.x, b4.x), 0.f);
      r.y = fmaxf(fmaf(di, acc.y + selfv.y, b4.y), 0.f);
      r.z = fmaxf(fmaf(di, acc.z + selfv.z, b4.z), 0.f);
      r.w = fmaxf(fmaf(di, acc.w + selfv.w, b4.w), 0.f);
    }
    *(float4*)&a_sh[g * LDP + (fg << 2)] = r;
  }
  __syncthreads();

  // ---- mm phase: wave computes output cols wave*16..wave*16+15 ----
  int lane = tid & 63;
  int wave = tid >> 6;
  int col = lane & 15, quad = lane >> 4;
  const float* arow = &a_sh[col * LDP + (quad << 3)];
  float4 a0 = *(const float4*)(arow);
  float4 a1 = *(const float4*)(arow + 4);
  float4 a2 = *(const float4*)(arow + 32);
  float4 a3 = *(const float4*)(arow + 36);
  bf16x8 ah[2], al[2];
  split8(a0, a1, ah[0], al[0]);
  split8(a2, a3, ah[1], al[1]);

  bf16x8 wh[2], wl[2];
#pragma unroll
  for (int q = 0; q < 2; ++q) {
    wh[q] = Wp1[((wave * 2 + q) * 2) * 64 + lane];
    wl[q] = Wp1[((wave * 2 + q) * 2 + 1) * 64 + lane];
  }
  f32x4 acc1 = (f32x4){0.f, 0.f, 0.f, 0.f};
#pragma unroll
  for (int q = 0; q < 2; ++q) {
    acc1 = __builtin_amdgcn_mfma_f32_16x16x32_bf16(ah[q], wh[q], acc1, 0, 0, 0);
    acc1 = __builtin_amdgcn_mfma_f32_16x16x32_bf16(ah[q], wl[q], acc1, 0, 0, 0);
    acc1 = __builtin_amdgcn_mfma_f32_16x16x32_bf16(al[q], wh[q], acc1, 0, 0, 0);
  }

  if constexpr (!HEAD) {
#pragma unroll
    for (int r = 0; r < 4; ++r) {
      int row = row0 + (quad << 2) + r;
      if (row < n) {
        ((unsigned short*)out)[(size_t)row * 64 + wave * 16 + col] =
            f2bf_rne(acc1[r] * dinv[row]);
      }
    }
  } else {
    // h4 = relu(acc1 + b1) -> a_sh (reused; all reads of a above are done
    // only after the barrier below)
    float bv1 = b1p[wave * 16 + col];
    __syncthreads();  // everyone finished reading a_sh
#pragma unroll
    for (int r = 0; r < 4; ++r) {
      a_sh[((quad << 2) + r) * LDP + wave * 16 + col] = fmaxf(acc1[r] + bv1, 0.f);
    }
    __syncthreads();
    const float* hrow = &a_sh[col * LDP + (quad << 3)];
    float4 h0 = *(const float4*)(hrow);
    float4 h1 = *(const float4*)(hrow + 4);
    float4 h2 = *(const float4*)(hrow + 32);
    float4 h3 = *(const float4*)(hrow + 36);
    bf16x8 ah2[2], al2[2];
    split8(h0, h1, ah2[0], al2[0]);
    split8(h2, h3, ah2[1], al2[1]);
    bf16x8 wh2[2], wl2[2];
#pragma unroll
    for (int q = 0; q < 2; ++q) {
      wh2[q] = Wp2[((wave * 2 + q) * 2) * 64 + lane];
      wl2[q] = Wp2[((wave * 2 + q) * 2 + 1) * 64 + lane];
    }
    f32x4 acc2 = (f32x4){0.f, 0.f, 0.f, 0.f};
#pragma unroll
    for (int q = 0; q < 2; ++q) {
      acc2 = __builtin_amdgcn_mfma_f32_16x16x32_bf16(ah2[q], wh2[q], acc2, 0, 0, 0);
      acc2 = __builtin_amdgcn_mfma_f32_16x16x32_bf16(ah2[q], wl2[q], acc2, 0, 0, 0);
      acc2 = __builtin_amdgcn_mfma_f32_16x16x32_bf16(al2[q], wh2[q], acc2, 0, 0, 0);
    }
    float bv2 = b2p[wave * 16 + col];
#pragma unroll
    for (int r = 0; r < 4; ++r) {
      int row = row0 + (quad << 2) + r;
      if (row < n) {
        ((float*)out)[(size_t)row * 64 + wave * 16 + col] = acc2[r] + bv2;
      }
    }
  }
}

extern "C" void kernel_launch(void* const* d_in, const int* in_sizes, int n_in,
                              void* d_out, int out_size, void* d_ws, size_t ws_size,
                              hipStream_t stream) {
  const float* x = (const float*)d_in[0];
  const int* ei = (const int*)d_in[1];  // int32 per harness convention
  const float* W1 = (const float*)d_in[2];
  const float* b1 = (const float*)d_in[3];
  const float* W2 = (const float*)d_in[4];
  const float* b2 = (const float*)d_in[5];
  const float* W3 = (const float*)d_in[6];
  const float* b3 = (const float*)d_in[7];
  const float* fw1 = (const float*)d_in[8];
  const float* fb1 = (const float*)d_in[9];
  const float* fw2 = (const float*)d_in[10];
  const float* fb2 = (const float*)d_in[11];
  float* out = (float*)d_out;

  const int N = in_sizes[0] / 64;
  const int E = in_sizes[1] / 2;
  const int K = CDIV(N, BKT_NODES);  // buckets (196 for N=100k)

  // workspace (~31 MB)
  char* w = (char*)d_ws;
  auto take = [&](size_t bytes) -> char* {
    char* p = w;
    w += (bytes + 255) & ~(size_t)255;
    return p;
  };
  float* dinv = (float*)take((size_t)N * 4);
  int* row_ptr = (int*)take((size_t)(N + 1) * 4);
  int* bcnt = (int*)take((size_t)256 * 4);
  int* srcs = (int*)take((size_t)E * 4);
  bf16x8* wpack = (bf16x8*)take((size_t)5 * 1024 * 16);                    // 80 KB
  unsigned short* hwsA = (unsigned short*)take((size_t)(N + 1) * 64 * 2);  // 12.8 MB (+zero row)
  unsigned short* hwsB = (unsigned short*)take((size_t)(N + 1) * 64 * 2);  // 12.8 MB
  int2* pairs = (int2*)hwsA;  // 11.6 MB alias; consumed before k_mm writes hwsA

  const int B = 256;

  // ---- weight prep (+bcnt zero) + CSR build (atomic-free) ----
  k_prep<<<6, 512, 0, stream>>>(W1, W2, W3, fw1, fw2, wpack, bcnt);
  k_bucket<<<512, B, 0, stream>>>(ei, bcnt, pairs, E);
  k_build<<<K, 1024, 0, stream>>>(pairs, bcnt, row_ptr, dinv, srcs, N, E, K);

  const int ntiles = CDIV(N, 16);
  const int MMG = CDIV(ntiles, 4);  // k_mm: 1 tile/wave, 4 waves/block

  // hws1 = bf16((x@W1)*dinv)
  k_mm<<<MMG, B, 0, stream>>>(x, wpack + 0 * 1024, dinv, hwsA, N);
  // h1 = relu(dinv*(agg+self)+b1); hws2 = bf16((h1@W2)*dinv)
  k_agg_mm<false><<<ntiles, B, 0, stream>>>(hwsA, dinv, row_ptr, srcs, b1,
                                            wpack + 1 * 1024, nullptr, nullptr, nullptr,
                                            hwsB, N);
  // h2; hws3 = bf16((h2@W3)*dinv)
  k_agg_mm<false><<<ntiles, B, 0, stream>>>(hwsB, dinv, row_ptr, srcs, b2,
                                            wpack + 2 * 1024, nullptr, nullptr, nullptr,
                                            hwsA, N);
  // h3; h4 = relu(h3@fw1+fb1); out = h4@fw2+fb2 (fp32)
  k_agg_mm<true><<<ntiles, B, 0, stream>>>(hwsA, dinv, row_ptr, srcs, b3,
                                           wpack + 3 * 1024, fb1, wpack + 4 * 1024, fb2,
                                           out, N);
}